// Round 10
// baseline (383.776 us; speedup 1.0000x reference)
//
#include <hip/hip_runtime.h>

typedef __bf16 bf16x8 __attribute__((ext_vector_type(8)));
typedef float f32x16 __attribute__((ext_vector_type(16)));

constexpr int K1 = 4096;
constexpr int N1 = 512;
constexpr int TT = 64;
constexpr int NC = 40;
constexpr float EPS  = 1e-4f;
constexpr float EPS2 = 1e-5f;
constexpr unsigned CAP  = 8192;
constexpr unsigned CAP2 = 1024;

// ws layout (bytes) — high-water 50.46 MB (unchanged)
constexpr size_t S_OFF    = 0;
constexpr size_t W1T_OFF  = 33554432;
constexpr size_t PKH_OFF  = 41943040;
constexpr size_t PKM_OFF  = 46137344;
constexpr size_t CNT_OFF  = 50331648;
constexpr size_t LIST_OFF = 50331904;
constexpr size_t YFIX_OFF  = PKH_OFF;
constexpr size_t W2PK_OFF  = PKM_OFF;
constexpr size_t SSUM_OFF  = PKM_OFF + 196608;
constexpr size_t LIST2_OFF = PKM_OFF + 237568;

union U8 { ushort u[8]; uint4 v; };
union BC { __bf16 b; ushort s; };

__device__ __forceinline__ void split_pair(float f0, float f1,
                                           unsigned& hp, unsigned& mp) {
  asm("v_cvt_pk_bf16_f32 %0, %1, %2" : "=v"(hp) : "v"(f0), "v"(f1));
  unsigned h0b = hp << 16;
  unsigned h1b = hp & 0xFFFF0000u;
  float m0 = f0 - __builtin_bit_cast(float, h0b);
  float m1 = f1 - __builtin_bit_cast(float, h1b);
  asm("v_cvt_pk_bf16_f32 %0, %1, %2" : "=v"(mp) : "v"(m0), "v"(m1));
}

// ---------------------------------------------------------------------------
// prep: W1 -> W1T (f32 [n][k]) + MFMA B-frag-ordered bf16 hi/mid packs.
// ---------------------------------------------------------------------------
__global__ __launch_bounds__(256) void prep(const float* __restrict__ W1,
                                            float* __restrict__ W1T,
                                            uint4* __restrict__ pkh,
                                            uint4* __restrict__ pkm) {
  __shared__ float tile[64][65];
  const int tid = threadIdx.x;
  const int kb = blockIdx.x * 64;
  const int nb = blockIdx.y * 64;
  const int r  = tid >> 2;
  const int c0 = (tid & 3) * 16;
  const float4* src = (const float4*)(W1 + (size_t)(kb + r) * N1 + nb + c0);
#pragma unroll
  for (int u = 0; u < 4; ++u) {
    float4 v = src[u];
    tile[r][c0 + u * 4 + 0] = v.x;
    tile[r][c0 + u * 4 + 1] = v.y;
    tile[r][c0 + u * 4 + 2] = v.z;
    tile[r][c0 + u * 4 + 3] = v.w;
  }
  __syncthreads();
  const size_t ob = (size_t)(nb + r) * K1 + kb + c0;
#pragma unroll
  for (int u = 0; u < 4; ++u) {
    float4 o = make_float4(tile[c0 + u * 4 + 0][r], tile[c0 + u * 4 + 1][r],
                           tile[c0 + u * 4 + 2][r], tile[c0 + u * 4 + 3][r]);
    *(float4*)(W1T + ob + u * 4) = o;
  }
#pragma unroll
  for (int sl = 0; sl < 2; ++sl) {
    const int slot = tid + sl * 256;
    const int frag_loc = slot >> 6, lane = slot & 63;
    const int kc_loc = frag_loc >> 1, s_loc = frag_loc & 1;
    const int n_loc = s_loc * 32 + (lane & 31);
    const int k_base = kc_loc * 16 + (lane >> 5) * 8;
    uint4 hh, mm;
    unsigned* hw = (unsigned*)&hh;
    unsigned* mw = (unsigned*)&mm;
#pragma unroll
    for (int p = 0; p < 4; ++p)
      split_pair(tile[k_base + 2 * p][n_loc], tile[k_base + 2 * p + 1][n_loc],
                 hw[p], mw[p]);
    const size_t f = (size_t)((nb >> 5) + s_loc) * 256 + (kb >> 4) + kc_loc;
    pkh[f * 64 + lane] = hh;
    pkm[f * 64 + lane] = mm;
  }
}

// ---------------------------------------------------------------------------
// gemm_fast R10: tile 64M x 128N, grid 1024 (4 blocks/CU, 16 waves/CU),
// 4 waves (wave tile 32M x 64N), BK=32, TWO PHASES per K-step (one per kh):
// each phase = barrier -> staging slice -> ds_read A -> B issue -> setprio+
// 6 MFMA + sched_barrier. A LDS double-buffered (8KB/buf), XOR-swizzled.
// ---------------------------------------------------------------------------
__global__ __launch_bounds__(256, 4) void gemm_fast(const float* __restrict__ x,
                                                    const uint4* __restrict__ pkh,
                                                    const uint4* __restrict__ pkm,
                                                    const float* __restrict__ b1,
                                                    float* __restrict__ S,
                                                    unsigned* __restrict__ cnt,
                                                    unsigned* __restrict__ list) {
  __shared__ __attribute__((aligned(16))) char lds[32768];
  // buffer b at lds + b*8192: hi [kh2][m32 2][64 lanes][16B] = 4KB, mid +4096
  float* const dS = (float*)lds;   // [64 t][128 n] f32, epilogue alias

  const int tid = threadIdx.x;
  const int lane = tid & 63, wid = tid >> 6;
  const int wm2 = wid & 1;         // m32 group
  const int wn2 = wid >> 1;        // n 64-half

  const int id = blockIdx.x;
  const int xcd = id & 7, sq = id >> 3;
  const int m_blk = xcd * 32 + (sq >> 2);   // 0..255 (= batch)
  const int n_blk = sq & 3;
  const int bm = m_blk * 64, bn = n_blk * 128;

  // A staging: thread -> row ar (0..63), k-chunk kq (0,8,16,24)
  const int ar = tid >> 2, kq = (tid & 3) * 8;
  const float* Ap = x + (size_t)(bm + ar) * K1 + kq;
  const int kh_w = kq >> 4, jh = (kq >> 3) & 1;
  int wbyte = (kh_w * 2 + (ar >> 5)) * 1024 + ((ar & 31) + 32 * jh) * 16;
  wbyte ^= ((kh_w * 2 + jh) & 3) << 4;

  // A frag read byte offsets (per kh), swizzle-consistent
  int rb[2];
#pragma unroll
  for (int kh = 0; kh < 2; ++kh)
    rb[kh] = ((kh * 2 + wm2) * 1024 + lane * 16) ^ (((kh * 2 + (lane >> 5)) & 3) << 4);

  // B frag pointers: s = n_blk*4 + wn2*2 + nt; frag f = s*256 + kc
  const uint4* pbh[2];
  const uint4* pbm[2];
#pragma unroll
  for (int nt = 0; nt < 2; ++nt) {
    const size_t base = (size_t)(n_blk * 4 + wn2 * 2 + nt) * 256 * 64 + lane;
    pbh[nt] = pkh + base;
    pbm[nt] = pkm + base;
  }

  f32x16 acc[2] = {};
  float4 av[2];
  uint4 sh, sm;                    // split regs for next K-step
  uint4 b0h[2], b0m[2], b1h[2], b1m[2];   // B sets kh0/kh1

  // prologue: load slice 0, B kh0; split+write buf0; load slice 1
  av[0] = *(const float4*)(Ap);
  av[1] = *(const float4*)(Ap + 4);
#pragma unroll
  for (int nt = 0; nt < 2; ++nt) { b0h[nt] = pbh[nt][0]; b0m[nt] = pbm[nt][0]; }
  {
    unsigned* hw = (unsigned*)&sh;
    unsigned* mw = (unsigned*)&sm;
    split_pair(av[0].x, av[0].y, hw[0], mw[0]);
    split_pair(av[0].z, av[0].w, hw[1], mw[1]);
    split_pair(av[1].x, av[1].y, hw[2], mw[2]);
    split_pair(av[1].z, av[1].w, hw[3], mw[3]);
    *(uint4*)(lds + wbyte)        = sh;
    *(uint4*)(lds + 4096 + wbyte) = sm;
  }
  av[0] = *(const float4*)(Ap + 32);
  av[1] = *(const float4*)(Ap + 36);

  for (int k0 = 0; k0 < K1; k0 += 32) {
    const int cur = (k0 >> 5) & 1;
    char* const bufc = lds + cur * 8192;
    char* const bufn = lds + (cur ^ 1) * 8192;
    const int kc = k0 >> 4;

    // ---- PHASE A (kh=0) ----
    __syncthreads();
    if (k0 + 32 < K1) {            // split next step's slice (VALU only)
      unsigned* hw = (unsigned*)&sh;
      unsigned* mw = (unsigned*)&sm;
      split_pair(av[0].x, av[0].y, hw[0], mw[0]);
      split_pair(av[0].z, av[0].w, hw[1], mw[1]);
      split_pair(av[1].x, av[1].y, hw[2], mw[2]);
      split_pair(av[1].z, av[1].w, hw[3], mw[3]);
    }
    {
      bf16x8 ah = *(const bf16x8*)(bufc + rb[0]);
      bf16x8 am = *(const bf16x8*)(bufc + 4096 + rb[0]);
      // issue B kh1 for this step
#pragma unroll
      for (int nt = 0; nt < 2; ++nt) {
        b1h[nt] = pbh[nt][(kc + 1) * 64];
        b1m[nt] = pbm[nt][(kc + 1) * 64];
      }
      __builtin_amdgcn_s_setprio(1);
#pragma unroll
      for (int nt = 0; nt < 2; ++nt) {
        const bf16x8 vbh = __builtin_bit_cast(bf16x8, b0h[nt]);
        const bf16x8 vbm = __builtin_bit_cast(bf16x8, b0m[nt]);
        acc[nt] = __builtin_amdgcn_mfma_f32_32x32x16_bf16(am, vbh, acc[nt], 0, 0, 0);
        acc[nt] = __builtin_amdgcn_mfma_f32_32x32x16_bf16(ah, vbm, acc[nt], 0, 0, 0);
        acc[nt] = __builtin_amdgcn_mfma_f32_32x32x16_bf16(ah, vbh, acc[nt], 0, 0, 0);
      }
      __builtin_amdgcn_s_setprio(0);
      __builtin_amdgcn_sched_barrier(0);
    }

    // ---- PHASE B (kh=1) ----
    __syncthreads();
    if (k0 + 32 < K1) {            // write next buffer + load slice k+2
      *(uint4*)(bufn + wbyte)        = sh;
      *(uint4*)(bufn + 4096 + wbyte) = sm;
      if (k0 + 64 < K1) {
        av[0] = *(const float4*)(Ap + k0 + 64);
        av[1] = *(const float4*)(Ap + k0 + 68);
      }
    }
    {
      bf16x8 ah = *(const bf16x8*)(bufc + rb[1]);
      bf16x8 am = *(const bf16x8*)(bufc + 4096 + rb[1]);
      // issue B kh0 for next step
      if (k0 + 32 < K1) {
#pragma unroll
        for (int nt = 0; nt < 2; ++nt) {
          b0h[nt] = pbh[nt][(kc + 2) * 64];
          b0m[nt] = pbm[nt][(kc + 2) * 64];
        }
      }
      __builtin_amdgcn_s_setprio(1);
#pragma unroll
      for (int nt = 0; nt < 2; ++nt) {
        const bf16x8 vbh = __builtin_bit_cast(bf16x8, b1h[nt]);
        const bf16x8 vbm = __builtin_bit_cast(bf16x8, b1m[nt]);
        acc[nt] = __builtin_amdgcn_mfma_f32_32x32x16_bf16(am, vbh, acc[nt], 0, 0, 0);
        acc[nt] = __builtin_amdgcn_mfma_f32_32x32x16_bf16(ah, vbm, acc[nt], 0, 0, 0);
        acc[nt] = __builtin_amdgcn_mfma_f32_32x32x16_bf16(ah, vbh, acc[nt], 0, 0, 0);
      }
      __builtin_amdgcn_s_setprio(0);
      __builtin_amdgcn_sched_barrier(0);
    }
  }

  // Epilogue: all 4 waves write disjoint dS quadrants; one batch per block.
  __syncthreads();
#pragma unroll
  for (int nt = 0; nt < 2; ++nt)
#pragma unroll
    for (int r = 0; r < 16; ++r) {
      const int row = wm2 * 32 + (r & 3) + 8 * (r >> 2) + 4 * (lane >> 5);
      const int col = wn2 * 64 + nt * 32 + (lane & 31);
      dS[row * 128 + col] = acc[nt][r];
    }
  __syncthreads();
  if (tid < 128) {
    const int n = tid;
    const int b = m_blk;
    const float bias = b1[bn + n];
    float mem = 0.0f, spk = 0.0f, mn = 1e9f;
    for (int t = 0; t < TT; ++t) {
      const float y = dS[t * 128 + n] + bias;
      mem = mem * 0.5f * (1.0f - spk) + y;
      const float d = mem - 1.0f;
      mn = fminf(mn, fabsf(d));
      spk = (d > 0.0f) ? 1.0f : 0.0f;
      S[((size_t)(b * TT + t)) * N1 + bn + n] = spk;
    }
    if (mn < EPS) {
      unsigned idx = atomicAdd(cnt, 1u);
      if (idx < CAP) list[idx] = ((unsigned)b << 16) | (unsigned)(bn + n);
    }
  }
}

// ---------------------------------------------------------------------------
// fixup_dots / fixup_apply / prep_w2 / head_mfma / fixup2 / pool: unchanged R9.
// ---------------------------------------------------------------------------
__global__ __launch_bounds__(256) void fixup_dots(const float* __restrict__ x,
                                                  const float* __restrict__ W1T,
                                                  const unsigned* __restrict__ cnt,
                                                  const unsigned* __restrict__ list,
                                                  double* __restrict__ yfix) {
  const int tid = threadIdx.x;
  const int lane = tid & 63, w = tid >> 6;
  const int count = (int)min(*cnt, CAP);

  for (int item = blockIdx.x; item < count * 4; item += gridDim.x) {
    const int e = item >> 2, quarter = item & 3;
    const unsigned ent = list[e];
    const int b = (int)(ent >> 16), n = (int)(ent & 0xffffu);
    const float4* wr = (const float4*)(W1T + (size_t)n * K1);
#pragma unroll
    for (int i = 0; i < 4; ++i) {
      const int t = quarter * 16 + w * 4 + i;
      const float4* xr = (const float4*)(x + ((size_t)(b * TT + t)) * K1);
      double p = 0.0;
#pragma unroll
      for (int j = 0; j < 16; ++j) {
        const float4 xv = xr[lane + 64 * j];
        const float4 wv = wr[lane + 64 * j];
        p += (double)xv.x * (double)wv.x + (double)xv.y * (double)wv.y +
             (double)xv.z * (double)wv.z + (double)xv.w * (double)wv.w;
      }
#pragma unroll
      for (int off = 1; off < 64; off <<= 1) p += __shfl_xor(p, off);
      if (lane == 0) yfix[(size_t)e * TT + t] = p;
    }
  }
}

__global__ __launch_bounds__(256) void fixup_apply(const double* __restrict__ yfix,
                                                   const float* __restrict__ b1,
                                                   const unsigned* __restrict__ cnt,
                                                   const unsigned* __restrict__ list,
                                                   float* __restrict__ S) {
  const int count = (int)min(*cnt, CAP);
  for (int e = blockIdx.x * 256 + threadIdx.x; e < count; e += gridDim.x * 256) {
    const unsigned ent = list[e];
    const int b = (int)(ent >> 16), n = (int)(ent & 0xffffu);
    double mem = 0.0, spk = 0.0;
    const double bias = (double)b1[n];
    for (int t = 0; t < TT; ++t) {
      const double y = yfix[(size_t)e * TT + t] + bias;
      mem = mem * 0.5 * (1.0 - spk) + y;
      spk = (mem > 1.0) ? 1.0 : 0.0;
      S[((size_t)(b * TT + t)) * N1 + n] = (float)spk;
    }
  }
}

__global__ __launch_bounds__(64) void prep_w2(const float* __restrict__ W2,
                                              uint4* __restrict__ p2h,
                                              uint4* __restrict__ p2m,
                                              uint4* __restrict__ p2l) {
  const int f = blockIdx.x;
  const int lane = threadIdx.x;
  const int s = f >> 5, kc = f & 31;
  const int n = s * 32 + (lane & 31);
  const int kb = kc * 16 + (lane >> 5) * 8;
  U8 hh, mm, ll;
#pragma unroll
  for (int j = 0; j < 8; ++j) {
    const float w = (n < NC) ? W2[(size_t)(kb + j) * NC + n] : 0.0f;
    __bf16 h = (__bf16)w;  float r1 = w - (float)h;
    __bf16 m = (__bf16)r1; float r2 = r1 - (float)m;
    __bf16 l = (__bf16)r2;
    BC ch; ch.b = h; BC cm; cm.b = m; BC cl; cl.b = l;
    hh.u[j] = ch.s; mm.u[j] = cm.s; ll.u[j] = cl.s;
  }
  p2h[(size_t)f * 64 + lane] = hh.v;
  p2m[(size_t)f * 64 + lane] = mm.v;
  p2l[(size_t)f * 64 + lane] = ll.v;
}

__global__ __launch_bounds__(256) void head_mfma(const float* __restrict__ S,
                                                 const uint4* __restrict__ p2h,
                                                 const uint4* __restrict__ p2m,
                                                 const uint4* __restrict__ p2l,
                                                 const float* __restrict__ b2,
                                                 float* __restrict__ ssum,
                                                 unsigned* __restrict__ cnt2,
                                                 unsigned* __restrict__ list2) {
  __shared__ __attribute__((aligned(16))) char lds[16384];
  float* const dS = (float*)lds;
  char* const buf = lds;

  const int tid = threadIdx.x;
  const int lane = tid & 63, wid = tid >> 6;
  const int wm2 = wid & 1, wn2 = wid >> 1;
  const int b = blockIdx.x;

  const int srow_ = tid >> 2, scol = (tid & 3) * 16;
  const float* Sp = S + ((size_t)(b * TT + srow_)) * N1 + scol;
  const int wb0 = srow_ * 128 + scol * 2;
  const int swz = (srow_ & 7) << 4;

  const int trow = wm2 * 32 + (lane & 31);
  const int aswz = (trow & 7) << 4;

  f32x16 acc = {};

  for (int step = 0; step < 8; ++step) {
    float4 v[4];
#pragma unroll
    for (int u = 0; u < 4; ++u) v[u] = *(const float4*)(Sp + step * 64 + u * 4);
    unsigned owv[8];
#pragma unroll
    for (int u = 0; u < 4; ++u) {
      unsigned d0, d1;
      split_pair(v[u].x, v[u].y, owv[2 * u], d0);
      split_pair(v[u].z, v[u].w, owv[2 * u + 1], d1);
      (void)d0; (void)d1;
    }
    uint4 o0 = make_uint4(owv[0], owv[1], owv[2], owv[3]);
    uint4 o1 = make_uint4(owv[4], owv[5], owv[6], owv[7]);
    __syncthreads();
    *(uint4*)(buf + ((wb0)      ^ swz)) = o0;
    *(uint4*)(buf + ((wb0 + 16) ^ swz)) = o1;
    __syncthreads();

#pragma unroll
    for (int kcl = 0; kcl < 4; ++kcl) {
      const int abyte = (trow * 128 + kcl * 32 + (lane >> 5) * 16) ^ aswz;
      const bf16x8 af = *(const bf16x8*)(buf + abyte);
      const size_t fidx = ((size_t)wn2 * 32 + step * 4 + kcl) * 64 + lane;
      const bf16x8 bh = __builtin_bit_cast(bf16x8, p2h[fidx]);
      const bf16x8 bm = __builtin_bit_cast(bf16x8, p2m[fidx]);
      const bf16x8 bl = __builtin_bit_cast(bf16x8, p2l[fidx]);
      acc = __builtin_amdgcn_mfma_f32_32x32x16_bf16(af, bl, acc, 0, 0, 0);
      acc = __builtin_amdgcn_mfma_f32_32x32x16_bf16(af, bm, acc, 0, 0, 0);
      acc = __builtin_amdgcn_mfma_f32_32x32x16_bf16(af, bh, acc, 0, 0, 0);
    }
  }

  __syncthreads();
#pragma unroll
  for (int r = 0; r < 16; ++r) {
    const int row = wm2 * 32 + (r & 3) + 8 * (r >> 2) + 4 * (lane >> 5);
    const int col = wn2 * 32 + (lane & 31);
    dS[row * 64 + col] = acc[r];
  }
  __syncthreads();

  if (tid < NC) {
    const float bias = b2[tid];
    float mem = 0.0f, spk = 0.0f, mn = 1e9f, ss = 0.0f;
    for (int t = 0; t < TT; ++t) {
      const float y = dS[t * 64 + tid] + bias;
      mem = mem * 0.5f * (1.0f - spk) + y;
      const float d = mem - 1.0f;
      mn = fminf(mn, fabsf(d));
      spk = (d > 0.0f) ? 1.0f : 0.0f;
      ss += spk;
    }
    ssum[b * NC + tid] = ss;
    if (mn < EPS2) {
      unsigned idx = atomicAdd(cnt2, 1u);
      if (idx < CAP2) list2[idx] = ((unsigned)b << 8) | (unsigned)tid;
    }
  }
}

__global__ __launch_bounds__(256) void fixup2(const float* __restrict__ S,
                                              const float* __restrict__ W2,
                                              const float* __restrict__ b2,
                                              const unsigned* __restrict__ cnt2,
                                              const unsigned* __restrict__ list2,
                                              float* __restrict__ ssum) {
  __shared__ float w2c[N1];
  __shared__ double y2[TT];
  const int tid = threadIdx.x;
  const int count = (int)min(*cnt2, CAP2);

  for (int e = blockIdx.x; e < count; e += gridDim.x) {
    const unsigned ent = list2[e];
    const int b = (int)(ent >> 8), c = (int)(ent & 255u);
    for (int h = tid; h < N1; h += 256) w2c[h] = W2[(size_t)h * NC + c];
    __syncthreads();
    const int t = tid >> 2, q = tid & 3;
    const float* sr = S + ((size_t)(b * TT + t)) * N1 + q * 128;
    double p = 0.0;
    for (int j = 0; j < 128; ++j) p += (double)sr[j] * (double)w2c[q * 128 + j];
    p += __shfl_xor(p, 1);
    p += __shfl_xor(p, 2);
    if (q == 0) y2[t] = p;
    __syncthreads();
    if (tid == 0) {
      double mem = 0.0, spk = 0.0, ss = 0.0;
      const double bias = (double)b2[c];
      for (int t2 = 0; t2 < TT; ++t2) {
        const double y = y2[t2] + bias;
        mem = mem * 0.5 * (1.0 - spk) + y;
        spk = (mem > 1.0) ? 1.0 : 0.0;
        ss += spk;
      }
      ssum[b * NC + c] = (float)ss;
    }
    __syncthreads();
  }
}

__global__ __launch_bounds__(256) void pool(const float* __restrict__ ssum,
                                            float* __restrict__ out) {
  const int i = blockIdx.x * 256 + threadIdx.x;
  if (i < 1024) {
    const int b = i >> 2, g = i & 3;
    double s = 0.0;
#pragma unroll
    for (int j = 0; j < 10; ++j) s += (double)ssum[b * NC + g * 10 + j];
    out[i] = (float)(s * (1.0 / 640.0));
  }
}

extern "C" void kernel_launch(void* const* d_in, const int* in_sizes, int n_in,
                              void* d_out, int out_size, void* d_ws, size_t ws_size,
                              hipStream_t stream) {
  const float* x  = (const float*)d_in[0];
  const float* W1 = (const float*)d_in[1];
  const float* b1 = (const float*)d_in[2];
  const float* W2 = (const float*)d_in[3];
  const float* b2 = (const float*)d_in[4];
  float* out = (float*)d_out;

  char* ws = (char*)d_ws;
  float*    Sb    = (float*)(ws + S_OFF);
  float*    W1T   = (float*)(ws + W1T_OFF);
  uint4*    pkh   = (uint4*)(ws + PKH_OFF);
  uint4*    pkm   = (uint4*)(ws + PKM_OFF);
  unsigned* cnt   = (unsigned*)(ws + CNT_OFF);
  unsigned* list  = (unsigned*)(ws + LIST_OFF);
  double*   yfix  = (double*)(ws + YFIX_OFF);
  uint4*    p2h   = (uint4*)(ws + W2PK_OFF);
  uint4*    p2m   = (uint4*)(ws + W2PK_OFF + 65536);
  uint4*    p2l   = (uint4*)(ws + W2PK_OFF + 131072);
  float*    ssumb = (float*)(ws + SSUM_OFF);
  unsigned* list2 = (unsigned*)(ws + LIST2_OFF);

  hipMemsetAsync(cnt, 0, 8, stream);
  prep<<<dim3(64, 8), dim3(256), 0, stream>>>(W1, W1T, pkh, pkm);
  gemm_fast<<<dim3(1024), dim3(256), 0, stream>>>(x, pkh, pkm, b1, Sb, cnt, list);
  fixup_dots<<<dim3(2048), dim3(256), 0, stream>>>(x, W1T, cnt, list, yfix);
  fixup_apply<<<dim3(16), dim3(256), 0, stream>>>(yfix, b1, cnt, list, Sb);
  prep_w2<<<dim3(64), dim3(64), 0, stream>>>(W2, p2h, p2m, p2l);
  head_mfma<<<dim3(256), dim3(256), 0, stream>>>(Sb, p2h, p2m, p2l, b2, ssumb, cnt + 1, list2);
  fixup2<<<dim3(64), dim3(256), 0, stream>>>(Sb, W2, b2, cnt + 1, list2, ssumb);
  pool<<<dim3(4), dim3(256), 0, stream>>>(ssumb, out);
}